// Round 15
// baseline (142.572 us; speedup 1.0000x reference)
//
#include <hip/hip_runtime.h>
#include <math.h>

#define B 16
#define C 128
#define H 32
#define W 512

typedef short bf16x8 __attribute__((ext_vector_type(8)));
typedef float f32x4 __attribute__((ext_vector_type(4)));

static __device__ inline unsigned short f2bf(float f) {
    unsigned u = __builtin_bit_cast(unsigned, f);
    u += 0x7fffu + ((u >> 16) & 1u);          // RNE
    return (unsigned short)(u >> 16);
}
// pack (lo=a, hi=b) as 2xbf16 in one u32 (RNE via HW cvt_pk)
static __device__ inline unsigned pack2(float a, float b) {
    unsigned u;
    asm("v_cvt_pk_bf16_f32 %0, %1, %2" : "=v"(u) : "v"(a), "v"(b));
    return u;
}
static __device__ inline float bflo(unsigned u) {
    return __builtin_bit_cast(float, u << 16);
}
static __device__ inline float bfhi(unsigned u) {
    return __builtin_bit_cast(float, u & 0xffff0000u);
}

// Build the 6 weight fragments for (g, o = wave*16+col) straight from wg f32.
#define W_FRAGS(wfr, wg, g, wave, col, q)                                      \
    {                                                                          \
        const float* wbase = (wg) + ((size_t)((g) * 64 + (wave) * 16 + (col))) * 192; \
        _Pragma("unroll") for (int tap = 0; tap < 3; ++tap)                    \
            _Pragma("unroll") for (int kk = 0; kk < 2; ++kk) {                 \
                const float* wp = wbase + ((kk) * 32 + (q) * 8) * 3 + tap;     \
                union { unsigned u[4]; bf16x8 v; } pk;                         \
                _Pragma("unroll") for (int e = 0; e < 4; ++e)                  \
                    pk.u[e] = pack2(wp[(2 * e) * 3], wp[(2 * e + 1) * 3]);     \
                wfr[tap][kk] = pk.v;                                           \
            }                                                                  \
    }

// Shared staging macros (used by both conv kernels; rely on local names).
#define P_LOADX(AA, HVV, h)                                                  \
    {                                                                        \
        const float4 v0 = *(const float4*)(xb0 + (h) * W);                   \
        const float4 v1 = *(const float4*)(xb0 + (size_t)(H * W) + (h) * W); \
        AA[0][0] = v0.x; AA[0][1] = v0.y; AA[0][2] = v0.z; AA[0][3] = v0.w;  \
        AA[1][0] = v1.x; AA[1][1] = v1.y; AA[1][2] = v1.z; AA[1][3] = v1.w;  \
        HVV = hvalid ? xh0[(h) * W] : 0.f;                                   \
    }
#define P_WRITEX(AA, HVV, buf)                                               \
    {                                                                        \
        _Pragma("unroll") for (int j = 0; j < 4; ++j)                        \
            *(unsigned*)((buf) + (size_t)(w0l + j + 1) * 144 + ci0 * 2) =    \
                pack2(AA[0][j], AA[1][j]);                                   \
        if (t < 128)                                                         \
            *(unsigned short*)((buf) + (size_t)(side ? 33 : 0) * 144 +       \
                               hci * 2) = f2bf(HVV);                         \
    }

// ---------------- Kernel A1: conv (bf16 MFMA) -> pools ONLY, h-split x2 -----------
// bx in [0,1024): f = bx&31 (g=f&1, b=f>>1), chunk = bx>>5: wq = chunk>>1, hq = chunk&1.
// 64 o x 32 w x 16 h in 8 two-h phases, ONE barrier per phase. Pool-C is deferred
// one phase and read from a bf16x2-packed ytile (w and w+16 share one u32).
__global__ __launch_bounds__(256) void conv_pools(
    const float* __restrict__ x, const float* __restrict__ wg,
    unsigned* __restrict__ pool3p, unsigned* __restrict__ pool1p,
    unsigned* __restrict__ pool2p) {
    __shared__ __align__(16) char xsb[2][2][34 * 144];       // 19,584 B
    __shared__ __align__(16) unsigned yt[2][2][16][68];      // 17,408 B

    const int bx = blockIdx.x;
    const int f  = bx & 31;
    const int g  = f & 1;
    const int b  = f >> 1;
    const int chunk = bx >> 5;
    const int wq = chunk >> 1;
    const int hq = chunk & 1;
    const int h0 = hq * 16;
    const int t  = threadIdx.x;
    const int lane = t & 63;
    const int col  = lane & 15;
    const int q    = lane >> 4;
    const int wave = t >> 6;

    bf16x8 wfr[3][2];
    W_FRAGS(wfr, wg, g, wave, col, q);

    float aA[2][4], aB[2][4];
    float hvA = 0.f, hvB = 0.f;
    const int w0l = (t & 7) * 4;
    const int ci0 = (t >> 3) * 2;
    const float* xb0 = x + (size_t)(b * C + g * 64 + ci0) * (H * W) + wq * 32 + w0l;
    const int side = (t >> 6) & 1;
    const int hci  = t & 63;
    const int gw   = wq * 32 + (side ? 32 : -1);
    const bool hvalid = (t < 128) && (side ? (wq < 15) : (wq > 0));
    const float* xh0 = x + (size_t)(b * C + g * 64 + hci) * (H * W) + gw;

    f32x4 mH[2], sH[2];
#pragma unroll
    for (int wt = 0; wt < 2; ++wt) {
        mH[wt] = (f32x4){-INFINITY, -INFINITY, -INFINITY, -INFINITY};
        sH[wt] = (f32x4){0.f, 0.f, 0.f, 0.f};
    }

// one h: MFMA + pool-H + pool-W + packed ytile dump
#define COMPUTEH(h, XBUF, PP, J)                                               \
    {                                                                          \
        f32x4 acc[2];                                                          \
        acc[0] = (f32x4){0.f, 0.f, 0.f, 0.f};                                  \
        acc[1] = (f32x4){0.f, 0.f, 0.f, 0.f};                                  \
        {                                                                      \
            const char* ab = (XBUF) + q * 16;                                  \
            _Pragma("unroll") for (int wt = 0; wt < 2; ++wt)                   \
                _Pragma("unroll") for (int kk = 0; kk < 2; ++kk)               \
                    _Pragma("unroll") for (int tap = 0; tap < 3; ++tap) {      \
                        const bf16x8 xf = *(const bf16x8*)(                    \
                            ab + (size_t)(wt * 16 + col + tap) * 144 +         \
                            kk * 64);                                          \
                        acc[wt] = __builtin_amdgcn_mfma_f32_16x16x32_bf16(     \
                            xf, wfr[tap][kk], acc[wt], 0, 0, 0);               \
                    }                                                          \
        }                                                                      \
        _Pragma("unroll") for (int wt = 0; wt < 2; ++wt)                       \
            _Pragma("unroll") for (int r = 0; r < 4; ++r) {                    \
                mH[wt][r] = fmaxf(mH[wt][r], acc[wt][r]);                      \
                sH[wt][r] += acc[wt][r];                                       \
            }                                                                  \
        {                                                                      \
            float m = acc[0][0], s = acc[0][0];                                \
            m = fmaxf(fmaxf(m, acc[0][1]), fmaxf(acc[0][2], acc[0][3]));       \
            s += acc[0][1] + acc[0][2] + acc[0][3];                            \
            _Pragma("unroll") for (int r = 0; r < 4; ++r) {                    \
                m = fmaxf(m, acc[1][r]);                                       \
                s += acc[1][r];                                                \
            }                                                                  \
            m = fmaxf(m, __shfl_xor(m, 16)); s += __shfl_xor(s, 16);           \
            m = fmaxf(m, __shfl_xor(m, 32)); s += __shfl_xor(s, 32);           \
            if (lane < 16)                                                     \
                pool3p[((size_t)(wq * B + b) * H + (h)) * C + g * 64 +         \
                       wave * 16 + lane] = pack2(m, s);                        \
        }                                                                      \
        _Pragma("unroll") for (int r = 0; r < 4; ++r)                          \
            yt[PP][J][q * 4 + r][wave * 16 + col] =                            \
                pack2(acc[0][r], acc[1][r]);                                   \
    }

// deferred pool-C: reduce over 64 o from packed ytile of pair PAIR (parity PP)
#define POOLC(PP, PAIR)                                                        \
    {                                                                          \
        const int j  = t >> 7;                                                 \
        const int rw = (t & 127) >> 3;                                         \
        const int e8 = t & 7;                                                  \
        const unsigned* yr = &yt[PP][j][rw][e8 * 8];                           \
        const uint4 u0 = *(const uint4*)yr;                                    \
        const uint4 u1 = *(const uint4*)(yr + 4);                              \
        float ml = bflo(u0.x), sl = ml, mh = bfhi(u0.x), sh = mh;              \
        ml = fmaxf(ml, bflo(u0.y)); sl += bflo(u0.y);                          \
        mh = fmaxf(mh, bfhi(u0.y)); sh += bfhi(u0.y);                          \
        ml = fmaxf(ml, bflo(u0.z)); sl += bflo(u0.z);                          \
        mh = fmaxf(mh, bfhi(u0.z)); sh += bfhi(u0.z);                          \
        ml = fmaxf(ml, bflo(u0.w)); sl += bflo(u0.w);                          \
        mh = fmaxf(mh, bfhi(u0.w)); sh += bfhi(u0.w);                          \
        ml = fmaxf(ml, bflo(u1.x)); sl += bflo(u1.x);                          \
        mh = fmaxf(mh, bfhi(u1.x)); sh += bfhi(u1.x);                          \
        ml = fmaxf(ml, bflo(u1.y)); sl += bflo(u1.y);                          \
        mh = fmaxf(mh, bfhi(u1.y)); sh += bfhi(u1.y);                          \
        ml = fmaxf(ml, bflo(u1.z)); sl += bflo(u1.z);                          \
        mh = fmaxf(mh, bfhi(u1.z)); sh += bfhi(u1.z);                          \
        ml = fmaxf(ml, bflo(u1.w)); sl += bflo(u1.w);                          \
        mh = fmaxf(mh, bfhi(u1.w)); sh += bfhi(u1.w);                          \
        _Pragma("unroll") for (int off = 1; off <= 4; off <<= 1) {             \
            ml = fmaxf(ml, __shfl_xor(ml, off)); sl += __shfl_xor(sl, off);    \
            mh = fmaxf(mh, __shfl_xor(mh, off)); sh += __shfl_xor(sh, off);    \
        }                                                                      \
        if (e8 == 0) {                                                         \
            const int h = h0 + 2 * (PAIR) + j;                                 \
            unsigned* dst =                                                    \
                pool1p + ((size_t)(g * B + b) * H + h) * W + wq * 32 + rw;     \
            dst[0]  = pack2(ml, sl);                                           \
            dst[16] = pack2(mh, sh);                                           \
        }                                                                      \
    }

#define PPHASE(p, P)                                                           \
    {                                                                          \
        if ((p) > 0) POOLC((P) ^ 1, (p) - 1);                                  \
        COMPUTEH(h0 + 2 * (p),     (char*)xsb[P][0], P, 0);                    \
        COMPUTEH(h0 + 2 * (p) + 1, (char*)xsb[P][1], P, 1);                    \
        if ((p) < 7) {                                                         \
            P_WRITEX(aA, hvA, (char*)xsb[(P) ^ 1][0]);                         \
            P_WRITEX(aB, hvB, (char*)xsb[(P) ^ 1][1]);                         \
        }                                                                      \
        if ((p) < 6) {                                                         \
            P_LOADX(aA, hvA, h0 + 2 * (p) + 4);                                \
            P_LOADX(aB, hvB, h0 + 2 * (p) + 5);                                \
        }                                                                      \
        __syncthreads();                                                       \
    }

    // prologue
    P_LOADX(aA, hvA, h0);
    P_LOADX(aB, hvB, h0 + 1);
    P_WRITEX(aA, hvA, (char*)xsb[0][0]);
    P_WRITEX(aB, hvB, (char*)xsb[0][1]);
    P_LOADX(aA, hvA, h0 + 2);
    P_LOADX(aB, hvB, h0 + 3);
    __syncthreads();

    PPHASE(0, 0); PPHASE(1, 1); PPHASE(2, 0); PPHASE(3, 1);
    PPHASE(4, 0); PPHASE(5, 1); PPHASE(6, 0); PPHASE(7, 1);
    POOLC(1, 7);                     // last pair, written before phase-7 barrier

#undef PPHASE
#undef POOLC
#undef COMPUTEH

    // ---- pool-H partial write -> pool2p[hq][B][C][W] u32 (m, raw sum) ----
    {
        const int o = g * 64 + wave * 16 + col;
        unsigned* p2 = pool2p + ((size_t)(hq * B + b) * C + o) * W + wq * 32 + q * 4;
#pragma unroll
        for (int wt = 0; wt < 2; ++wt) {
            uint4 pk;
            pk.x = pack2(mH[wt][0], sH[wt][0]);
            pk.y = pack2(mH[wt][1], sH[wt][1]);
            pk.z = pack2(mH[wt][2], sH[wt][2]);
            pk.w = pack2(mH[wt][3], sH[wt][3]);
            *(uint4*)(p2 + wt * 16) = pk;
        }
    }
}

// ---------------- Kernel A2: conv recompute + gate multiply -> out ----------------
// bx in [0,2048): f = bx&31 (g=f&1, b=f>>1), chunk = bx>>5: wq = chunk>>2, hq = chunk&3.
// 64 o x 32 w x 8 h in 4 two-h phases, one barrier per phase.
__global__ __launch_bounds__(256) void conv_apply(
    const float* __restrict__ x, const float* __restrict__ wg,
    const float* __restrict__ s1, const float* __restrict__ s2,
    const float* __restrict__ s3, float* __restrict__ out) {
    __shared__ __align__(16) char xsb[2][2][34 * 144];   // 19,584 B

    const int bx = blockIdx.x;
    const int f  = bx & 31;
    const int g  = f & 1;
    const int b  = f >> 1;
    const int chunk = bx >> 5;
    const int wq = chunk >> 2;
    const int hq = chunk & 3;
    const int h0 = hq * 8;
    const int t  = threadIdx.x;
    const int lane = t & 63;
    const int col  = lane & 15;
    const int q    = lane >> 4;
    const int wave = t >> 6;

    bf16x8 wfr[3][2];
    W_FRAGS(wfr, wg, g, wave, col, q);

    float aA[2][4], aB[2][4];
    float hvA = 0.f, hvB = 0.f;
    const int w0l = (t & 7) * 4;
    const int ci0 = (t >> 3) * 2;
    const float* xb0 = x + (size_t)(b * C + g * 64 + ci0) * (H * W) + wq * 32 + w0l;
    const int side = (t >> 6) & 1;
    const int hci  = t & 63;
    const int gw   = wq * 32 + (side ? 32 : -1);
    const bool hvalid = (t < 128) && (side ? (wq < 15) : (wq > 0));
    const float* xh0 = x + (size_t)(b * C + g * 64 + hci) * (H * W) + gw;

    // hoisted gates: s2[b, o, w] (h-independent)
    const int o = g * 64 + wave * 16 + col;
    const float4 g2a = *(const float4*)(s2 + ((size_t)b * C + o) * W + wq * 32 + q * 4);
    const float4 g2b = *(const float4*)(s2 + ((size_t)b * C + o) * W + wq * 32 + q * 4 + 16);

#define ASTEPH(h, XBUF)                                                        \
    {                                                                          \
        f32x4 acc[2];                                                          \
        acc[0] = (f32x4){0.f, 0.f, 0.f, 0.f};                                  \
        acc[1] = (f32x4){0.f, 0.f, 0.f, 0.f};                                  \
        {                                                                      \
            const char* ab = (XBUF) + q * 16;                                  \
            _Pragma("unroll") for (int wt = 0; wt < 2; ++wt)                   \
                _Pragma("unroll") for (int kk = 0; kk < 2; ++kk)               \
                    _Pragma("unroll") for (int tap = 0; tap < 3; ++tap) {      \
                        const bf16x8 xf = *(const bf16x8*)(                    \
                            ab + (size_t)(wt * 16 + col + tap) * 144 +         \
                            kk * 64);                                          \
                        acc[wt] = __builtin_amdgcn_mfma_f32_16x16x32_bf16(     \
                            xf, wfr[tap][kk], acc[wt], 0, 0, 0);               \
                    }                                                          \
        }                                                                      \
        const float4 g1a = *(const float4*)(s1 + ((size_t)b * H + (h)) * W +   \
                                            wq * 32 + q * 4);                  \
        const float4 g1b = *(const float4*)(s1 + ((size_t)b * H + (h)) * W +   \
                                            wq * 32 + q * 4 + 16);             \
        const float g3v = s3[((size_t)b * H + (h)) * C + o];                   \
        const float k   = 1.f / 3.f;                                           \
        float* ob =                                                            \
            out + ((size_t)(b * C + o) * H + (h)) * W + wq * 32 + q * 4;       \
        f32x4 o0, o1;                                                          \
        o0[0] = acc[0][0] * (g1a.x + g2a.x + g3v) * k;                         \
        o0[1] = acc[0][1] * (g1a.y + g2a.y + g3v) * k;                         \
        o0[2] = acc[0][2] * (g1a.z + g2a.z + g3v) * k;                         \
        o0[3] = acc[0][3] * (g1a.w + g2a.w + g3v) * k;                         \
        o1[0] = acc[1][0] * (g1b.x + g2b.x + g3v) * k;                         \
        o1[1] = acc[1][1] * (g1b.y + g2b.y + g3v) * k;                         \
        o1[2] = acc[1][2] * (g1b.z + g2b.z + g3v) * k;                         \
        o1[3] = acc[1][3] * (g1b.w + g2b.w + g3v) * k;                         \
        *(f32x4*)ob        = o0;                                               \
        *(f32x4*)(ob + 16) = o1;                                               \
    }

#define APHASE(p, P)                                                           \
    {                                                                          \
        ASTEPH(h0 + 2 * (p),     (char*)xsb[P][0]);                            \
        ASTEPH(h0 + 2 * (p) + 1, (char*)xsb[P][1]);                            \
        if ((p) < 3) {                                                         \
            P_WRITEX(aA, hvA, (char*)xsb[(P) ^ 1][0]);                         \
            P_WRITEX(aB, hvB, (char*)xsb[(P) ^ 1][1]);                         \
        }                                                                      \
        if ((p) < 2) {                                                         \
            P_LOADX(aA, hvA, h0 + 2 * (p) + 4);                                \
            P_LOADX(aB, hvB, h0 + 2 * (p) + 5);                                \
        }                                                                      \
        __syncthreads();                                                       \
    }

    P_LOADX(aA, hvA, h0);
    P_LOADX(aB, hvB, h0 + 1);
    P_WRITEX(aA, hvA, (char*)xsb[0][0]);
    P_WRITEX(aB, hvB, (char*)xsb[0][1]);
    P_LOADX(aA, hvA, h0 + 2);
    P_LOADX(aB, hvB, h0 + 3);
    __syncthreads();

    APHASE(0, 0); APHASE(1, 1); APHASE(2, 0); APHASE(3, 1);

#undef APHASE
#undef ASTEPH
}
#undef P_LOADX
#undef P_WRITEX

// ---------------- combine: pool3 only (16-way) ----------------
__global__ __launch_bounds__(256) void combine(const unsigned* __restrict__ p3p,
                                               float* __restrict__ pool3) {
    const int n = blockIdx.x * 256 + threadIdx.x;   // over B*H*C
    const int b = n >> 12;
    const int o = n & 4095;
    float m = -INFINITY, s = 0.f;
#pragma unroll
    for (int wq = 0; wq < 16; ++wq) {
        const unsigned u = p3p[(size_t)(wq * B + b) * 4096 + o];
        m = fmaxf(m, bflo(u));
        s += bfhi(u);
    }
    pool3[((size_t)(b * 2 + 0) * H * C) + o] = m;
    pool3[((size_t)(b * 2 + 1) * H * C) + o] = s * (1.f / W);
}

// ---------------- gates: three 7x7 conv (2->1) + sigmoid in one kernel ------------
__global__ __launch_bounds__(256) void gates(
    const unsigned* __restrict__ pool1p, const unsigned* __restrict__ pool2p,
    const float* __restrict__ pool3, const float* __restrict__ w1,
    const float* __restrict__ w2, const float* __restrict__ w3,
    float* __restrict__ s1, float* __restrict__ s2, float* __restrict__ s3) {
    const int bid = blockIdx.x;
    if (bid < 256) {
        // ---- s1: 2-way packed partials, P=H, Q=W, mean scale 1/C ----
        const int n  = bid * 256 + threadIdx.x;     // over B*H*W/4
        const int q0 = (n & 127) * 4;
        const int p  = (n >> 7) & 31;
        const int b  = n >> 12;
        float acc0 = 0.f, acc1 = 0.f, acc2 = 0.f, acc3 = 0.f;
#pragma unroll
        for (int i = 0; i < 7; ++i) {
            const int pp = p + i - 3;
            if (pp < 0 || pp >= H) continue;
            const unsigned* r0 = pool1p + ((size_t)b * H + pp) * W;
            const unsigned* r1 = r0 + 262144;
            float vm[10], vs[10];
#pragma unroll
            for (int j = 0; j < 10; ++j) {
                const int qq = q0 + j - 3;
                const unsigned u0 = (qq >= 0 && qq < W) ? r0[qq] : 0u;
                const unsigned u1 = (qq >= 0 && qq < W) ? r1[qq] : 0u;
                vm[j] = fmaxf(bflo(u0), bflo(u1));
                vs[j] = (bfhi(u0) + bfhi(u1)) * (1.f / C);
            }
            const float* wr0 = w1 + i * 7;
            const float* wr1 = w1 + 49 + i * 7;
#pragma unroll
            for (int j = 0; j < 7; ++j) {
                const float wv0 = wr0[j], wv1 = wr1[j];
                acc0 += vm[j]     * wv0 + vs[j]     * wv1;
                acc1 += vm[j + 1] * wv0 + vs[j + 1] * wv1;
                acc2 += vm[j + 2] * wv0 + vs[j + 2] * wv1;
                acc3 += vm[j + 3] * wv0 + vs[j + 3] * wv1;
            }
        }
        float4 ov;
        ov.x = 1.f / (1.f + expf(-acc0));
        ov.y = 1.f / (1.f + expf(-acc1));
        ov.z = 1.f / (1.f + expf(-acc2));
        ov.w = 1.f / (1.f + expf(-acc3));
        *(float4*)(s1 + (size_t)n * 4) = ov;
    } else if (bid < 1280) {
        // ---- s2: 2-way packed partials, P=C, Q=W, mean scale 1/H ----
        const int n  = (bid - 256) * 256 + threadIdx.x;   // over B*C*W/4
        const int q0 = (n & 127) * 4;
        const int p  = (n >> 7) & 127;
        const int b  = n >> 14;
        float acc0 = 0.f, acc1 = 0.f, acc2 = 0.f, acc3 = 0.f;
#pragma unroll
        for (int i = 0; i < 7; ++i) {
            const int pp = p + i - 3;
            if (pp < 0 || pp >= C) continue;
            const unsigned* r0 = pool2p + ((size_t)b * C + pp) * W;
            const unsigned* r1 = r0 + 1048576;
            float vm[10], vs[10];
#pragma unroll
            for (int j = 0; j < 10; ++j) {
                const int qq = q0 + j - 3;
                const unsigned u0 = (qq >= 0 && qq < W) ? r0[qq] : 0u;
                const unsigned u1 = (qq >= 0 && qq < W) ? r1[qq] : 0u;
                vm[j] = fmaxf(bflo(u0), bflo(u1));
                vs[j] = (bfhi(u0) + bfhi(u1)) * (1.f / H);
            }
            const float* wr0 = w2 + i * 7;
            const float* wr1 = w2 + 49 + i * 7;
#pragma unroll
            for (int j = 0; j < 7; ++j) {
                const float wv0 = wr0[j], wv1 = wr1[j];
                acc0 += vm[j]     * wv0 + vs[j]     * wv1;
                acc1 += vm[j + 1] * wv0 + vs[j + 1] * wv1;
                acc2 += vm[j + 2] * wv0 + vs[j + 2] * wv1;
                acc3 += vm[j + 3] * wv0 + vs[j + 3] * wv1;
            }
        }
        float4 ov;
        ov.x = 1.f / (1.f + expf(-acc0));
        ov.y = 1.f / (1.f + expf(-acc1));
        ov.z = 1.f / (1.f + expf(-acc2));
        ov.w = 1.f / (1.f + expf(-acc3));
        *(float4*)(s2 + (size_t)n * 4) = ov;
    } else {
        // ---- s3: combined pool3 (f32 2 planes), P=H, Q=C ----
        const int n  = (bid - 1280) * 256 + threadIdx.x;  // over B*H*C/4
        const int q0 = (n & 31) * 4;
        const int p  = (n >> 5) & 31;
        const int b  = n >> 10;
        float acc0 = 0.f, acc1 = 0.f, acc2 = 0.f, acc3 = 0.f;
#pragma unroll
        for (int c2 = 0; c2 < 2; ++c2) {
#pragma unroll
            for (int i = 0; i < 7; ++i) {
                const int pp = p + i - 3;
                if (pp < 0 || pp >= H) continue;
                const float* row = pool3 + ((size_t)(b * 2 + c2) * H + pp) * C;
                float win[10];
#pragma unroll
                for (int j = 0; j < 10; ++j) {
                    const int qq = q0 + j - 3;
                    win[j] = (qq >= 0 && qq < C) ? row[qq] : 0.f;
                }
                const float* wr = w3 + c2 * 49 + i * 7;
#pragma unroll
                for (int j = 0; j < 7; ++j) {
                    const float wv = wr[j];
                    acc0 += win[j]     * wv;
                    acc1 += win[j + 1] * wv;
                    acc2 += win[j + 2] * wv;
                    acc3 += win[j + 3] * wv;
                }
            }
        }
        float4 ov;
        ov.x = 1.f / (1.f + expf(-acc0));
        ov.y = 1.f / (1.f + expf(-acc1));
        ov.z = 1.f / (1.f + expf(-acc2));
        ov.w = 1.f / (1.f + expf(-acc3));
        *(float4*)(s3 + (size_t)n * 4) = ov;
    }
}

extern "C" void kernel_launch(void* const* d_in, const int* in_sizes, int n_in,
                              void* d_out, int out_size, void* d_ws, size_t ws_size,
                              hipStream_t stream) {
    const float* x  = (const float*)d_in[0];
    const float* wg = (const float*)d_in[1];
    const float* w1 = (const float*)d_in[2];
    const float* w2 = (const float*)d_in[3];
    const float* w3 = (const float*)d_in[4];
    float* out = (float*)d_out;
    float* ws  = (float*)d_ws;

    // Workspace (float-slot offsets), total 4,141,056 floats = 16.56 MB:
    //  [0,       524288): pool1p u32 [2][B][H][W]   (live until gates)
    //  [524288, 1572864): pool3p u32 [16][B][H][C]  -> s2 reuses after combine
    //  [1572864,3670016): pool2p u32 [2][B][C][W]   (live until gates)
    //  [3670016,3801088): pool3 f32 [B][2][H][C]
    //  [3813376,4075520): s1 f32 [B][H][W]
    //  [4075520,4141056): s3 f32 [B][H][C]
    unsigned* pool1p = (unsigned*)ws;
    unsigned* pool3p = (unsigned*)(ws + 524288);
    unsigned* pool2p = (unsigned*)(ws + 1572864);
    float* pool3 = ws + 3670016;
    float* s1 = ws + 3813376;
    float* s3 = ws + 4075520;
    float* s2 = ws + 524288;          // overlays dead pool3p after combine

    conv_pools<<<dim3(1024), 256, 0, stream>>>(x, wg, pool3p, pool1p, pool2p);
    combine<<<dim3(256), 256, 0, stream>>>(pool3p, pool3);
    gates<<<dim3(1344), 256, 0, stream>>>(pool1p, pool2p, pool3, w1, w2, w3, s1, s2, s3);
    conv_apply<<<dim3(2048), 256, 0, stream>>>(x, wg, s1, s2, s3, out);
}

// Round 16
// 135.049 us; speedup vs baseline: 1.0557x; 1.0557x over previous
//
#include <hip/hip_runtime.h>
#include <math.h>

#define B 16
#define C 128
#define H 32
#define W 512

typedef short bf16x4 __attribute__((ext_vector_type(4)));
typedef short bf16x8 __attribute__((ext_vector_type(8)));
typedef float f32x4 __attribute__((ext_vector_type(4)));

static __device__ inline unsigned short f2bf(float f) {
    unsigned u = __builtin_bit_cast(unsigned, f);
    u += 0x7fffu + ((u >> 16) & 1u);          // RNE
    return (unsigned short)(u >> 16);
}
// pack (lo=a, hi=b) as 2xbf16 in one u32 (RNE via HW cvt_pk)
static __device__ inline unsigned pack2(float a, float b) {
    unsigned u;
    asm("v_cvt_pk_bf16_f32 %0, %1, %2" : "=v"(u) : "v"(a), "v"(b));
    return u;
}
static __device__ inline float bflo(unsigned u) {
    return __builtin_bit_cast(float, u << 16);
}
static __device__ inline float bfhi(unsigned u) {
    return __builtin_bit_cast(float, u & 0xffff0000u);
}

// Build the 6 weight fragments for (g, o = wave*16+col) straight from wg f32.
// wfr[tap][kk][e] = bf16(wg[(g*64+o)*192 + (kk*32 + q*8 + e)*3 + tap]).
#define W_FRAGS(wfr, wg, g, wave, col, q)                                      \
    {                                                                          \
        const float* wbase = (wg) + ((size_t)((g) * 64 + (wave) * 16 + (col))) * 192; \
        _Pragma("unroll") for (int tap = 0; tap < 3; ++tap)                    \
            _Pragma("unroll") for (int kk = 0; kk < 2; ++kk) {                 \
                const float* wp = wbase + ((kk) * 32 + (q) * 8) * 3 + tap;     \
                union { unsigned u[4]; bf16x8 v; } pk;                         \
                _Pragma("unroll") for (int e = 0; e < 4; ++e)                  \
                    pk.u[e] = pack2(wp[(2 * e) * 3], wp[(2 * e + 1) * 3]);     \
                wfr[tap][kk] = pk.v;                                           \
            }                                                                  \
    }

// ---------------- Kernel A1: conv (bf16 MFMA) -> pools ONLY, h-split x2 -----------
// bx in [0,1024): f = bx&31 (g=f&1, b=f>>1), chunk = bx>>5: wq = chunk>>1, hq = chunk&1.
// 64 o x 32 w x 16 h. One barrier per h; 3-deep load pipeline (2 reg sets).
__global__ __launch_bounds__(256) void conv_pools(
    const float* __restrict__ x, const float* __restrict__ wg,
    unsigned* __restrict__ pool3p, unsigned* __restrict__ pool1p,
    unsigned* __restrict__ pool2p) {
    __shared__ __align__(16) char xsb[2][34 * 144];   // 9,792 B
    __shared__ __align__(16) float ytile[2][32][68];  // 17,408 B

    const int bx = blockIdx.x;
    const int f  = bx & 31;
    const int g  = f & 1;
    const int b  = f >> 1;
    const int chunk = bx >> 5;
    const int wq = chunk >> 1;
    const int hq = chunk & 1;
    const int h0 = hq * 16;
    const int t  = threadIdx.x;
    const int lane = t & 63;
    const int col  = lane & 15;
    const int q    = lane >> 4;
    const int wave = t >> 6;

    bf16x8 wfr[3][2];
    W_FRAGS(wfr, wg, g, wave, col, q);

    // two staging register sets
    float a0[2][4], a1[2][4];
    float hv0 = 0.f, hv1 = 0.f;
    const int w0l = (t & 7) * 4;
    const int ci0 = (t >> 3) * 2;
    const float* xb0 = x + (size_t)(b * C + g * 64 + ci0) * (H * W) + wq * 32 + w0l;
    const int side = (t >> 6) & 1;
    const int hci  = t & 63;
    const int gw   = wq * 32 + (side ? 32 : -1);
    const bool hvalid = (t < 128) && (side ? (wq < 15) : (wq > 0));
    const float* xh0 = x + (size_t)(b * C + g * 64 + hci) * (H * W) + gw;

#define P_LOADX(AA, HVV, h)                                                  \
    {                                                                        \
        const float4 v0 = *(const float4*)(xb0 + (h) * W);                   \
        const float4 v1 = *(const float4*)(xb0 + (size_t)(H * W) + (h) * W); \
        AA[0][0] = v0.x; AA[0][1] = v0.y; AA[0][2] = v0.z; AA[0][3] = v0.w;  \
        AA[1][0] = v1.x; AA[1][1] = v1.y; AA[1][2] = v1.z; AA[1][3] = v1.w;  \
        HVV = hvalid ? xh0[(h) * W] : 0.f;                                   \
    }
#define P_WRITEX(AA, HVV, buf)                                               \
    {                                                                        \
        _Pragma("unroll") for (int j = 0; j < 4; ++j)                        \
            *(unsigned*)((buf) + (size_t)(w0l + j + 1) * 144 + ci0 * 2) =    \
                pack2(AA[0][j], AA[1][j]);                                   \
        if (t < 128)                                                         \
            *(unsigned short*)((buf) + (size_t)(side ? 33 : 0) * 144 +       \
                               hci * 2) = f2bf(HVV);                         \
    }

    f32x4 mH[2], sH[2];
#pragma unroll
    for (int wt = 0; wt < 2; ++wt) {
        mH[wt] = (f32x4){-INFINITY, -INFINITY, -INFINITY, -INFINITY};
        sH[wt] = (f32x4){0.f, 0.f, 0.f, 0.f};
    }

    const int wl = t >> 3;              // w_local 0..31
    const int e  = t & 7;               // o-octet

    // prologue: 3-deep
    P_LOADX(a0, hv0, h0);
    P_WRITEX(a0, hv0, xsb[0]);
    P_LOADX(a1, hv1, h0 + 1);
    P_LOADX(a0, hv0, h0 + 2);
    __syncthreads();

    // body macro: one h step, compile-time parity
#define P_STEP(hh, CUR, AW, HW, AL, HL)                                        \
    {                                                                          \
        const int h = h0 + (hh);                                               \
        f32x4 acc[2];                                                          \
        acc[0] = (f32x4){0.f, 0.f, 0.f, 0.f};                                  \
        acc[1] = (f32x4){0.f, 0.f, 0.f, 0.f};                                  \
        {                                                                      \
            const char* ab = xsb[CUR] + q * 16;                                \
            _Pragma("unroll") for (int wt = 0; wt < 2; ++wt)                   \
                _Pragma("unroll") for (int kk = 0; kk < 2; ++kk)               \
                    _Pragma("unroll") for (int tap = 0; tap < 3; ++tap) {      \
                        const bf16x8 xf = *(const bf16x8*)(                    \
                            ab + (size_t)(wt * 16 + col + tap) * 144 +         \
                            kk * 64);                                          \
                        acc[wt] = __builtin_amdgcn_mfma_f32_16x16x32_bf16(     \
                            xf, wfr[tap][kk], acc[wt], 0, 0, 0);               \
                    }                                                          \
        }                                                                      \
        _Pragma("unroll") for (int wt = 0; wt < 2; ++wt)                       \
            _Pragma("unroll") for (int r = 0; r < 4; ++r) {                    \
                mH[wt][r] = fmaxf(mH[wt][r], acc[wt][r]);                      \
                sH[wt][r] += acc[wt][r];                                       \
            }                                                                  \
        {                                                                      \
            float m = acc[0][0], s = acc[0][0];                                \
            m = fmaxf(fmaxf(m, acc[0][1]), fmaxf(acc[0][2], acc[0][3]));       \
            s += acc[0][1] + acc[0][2] + acc[0][3];                            \
            _Pragma("unroll") for (int r = 0; r < 4; ++r) {                    \
                m = fmaxf(m, acc[1][r]);                                       \
                s += acc[1][r];                                                \
            }                                                                  \
            m = fmaxf(m, __shfl_xor(m, 16)); s += __shfl_xor(s, 16);           \
            m = fmaxf(m, __shfl_xor(m, 32)); s += __shfl_xor(s, 32);           \
            if (lane < 16)                                                     \
                pool3p[((size_t)(wq * B + b) * H + h) * C + g * 64 +           \
                       wave * 16 + lane] = pack2(m, s);                        \
        }                                                                      \
        _Pragma("unroll") for (int wt = 0; wt < 2; ++wt)                       \
            _Pragma("unroll") for (int r = 0; r < 4; ++r)                      \
                ytile[CUR][wt * 16 + q * 4 + r][wave * 16 + col] = acc[wt][r]; \
        if ((hh) < 15) P_WRITEX(AW, HW, xsb[(CUR) ^ 1]);                       \
        if ((hh) < 13) P_LOADX(AL, HL, h0 + (hh) + 3);                         \
        __syncthreads();                                                       \
        {                                                                      \
            const f32x4 v0 = *(const f32x4*)&ytile[CUR][wl][e * 8];            \
            const f32x4 v1 = *(const f32x4*)&ytile[CUR][wl][e * 8 + 4];        \
            float m = fmaxf(fmaxf(v0[0], v0[1]), fmaxf(v0[2], v0[3]));         \
            float s = v0[0] + v0[1] + v0[2] + v0[3];                           \
            m = fmaxf(m, fmaxf(fmaxf(v1[0], v1[1]), fmaxf(v1[2], v1[3])));     \
            s += v1[0] + v1[1] + v1[2] + v1[3];                                \
            _Pragma("unroll") for (int off = 1; off <= 4; off <<= 1) {         \
                m = fmaxf(m, __shfl_xor(m, off));                              \
                s += __shfl_xor(s, off);                                       \
            }                                                                  \
            if (e == 0)                                                        \
                pool1p[((size_t)(g * B + b) * H + h) * W + wq * 32 + wl] =     \
                    pack2(m, s);                                               \
        }                                                                      \
    }

    for (int hh = 0; hh < 16; hh += 2) {
        P_STEP(hh,     0, a1, hv1, a1, hv1);   // consume buf0; write h+1 (S1); load h+3 -> S1
        P_STEP(hh + 1, 1, a0, hv0, a0, hv0);   // consume buf1; write h+2 (S0); load h+4 -> S0
    }
#undef P_STEP

    // ---- pool-H partial write -> pool2p[hq][B][C][W] u32 (m, raw sum) ----
    {
        const int o = g * 64 + wave * 16 + col;
        unsigned* p2 = pool2p + ((size_t)(hq * B + b) * C + o) * W + wq * 32 + q * 4;
#pragma unroll
        for (int wt = 0; wt < 2; ++wt) {
            uint4 pk;
            pk.x = pack2(mH[wt][0], sH[wt][0]);
            pk.y = pack2(mH[wt][1], sH[wt][1]);
            pk.z = pack2(mH[wt][2], sH[wt][2]);
            pk.w = pack2(mH[wt][3], sH[wt][3]);
            *(uint4*)(p2 + wt * 16) = pk;
        }
    }
}

// ---------------- Kernel A2: conv recompute + gate multiply -> out ----------------
// bx in [0,2048): f = bx&31 (g=f&1, b=f>>1), chunk = bx>>5: wq = chunk>>2, hq = chunk&3.
// 64 o x 32 w x 8 h. One barrier per h; 3-deep load pipeline.
__global__ __launch_bounds__(256) void conv_apply(
    const float* __restrict__ x, const float* __restrict__ wg,
    const float* __restrict__ s1, const float* __restrict__ s2,
    const float* __restrict__ s3, float* __restrict__ out) {
    __shared__ __align__(16) char xsb[2][34 * 144];   // 9,792 B

    const int bx = blockIdx.x;
    const int f  = bx & 31;
    const int g  = f & 1;
    const int b  = f >> 1;
    const int chunk = bx >> 5;
    const int wq = chunk >> 2;
    const int hq = chunk & 3;
    const int h0 = hq * 8;
    const int t  = threadIdx.x;
    const int lane = t & 63;
    const int col  = lane & 15;
    const int q    = lane >> 4;
    const int wave = t >> 6;

    bf16x8 wfr[3][2];
    W_FRAGS(wfr, wg, g, wave, col, q);

    float a0[2][4], a1[2][4];
    float hv0 = 0.f, hv1 = 0.f;
    const int w0l = (t & 7) * 4;
    const int ci0 = (t >> 3) * 2;
    const float* xb0 = x + (size_t)(b * C + g * 64 + ci0) * (H * W) + wq * 32 + w0l;
    const int side = (t >> 6) & 1;
    const int hci  = t & 63;
    const int gw   = wq * 32 + (side ? 32 : -1);
    const bool hvalid = (t < 128) && (side ? (wq < 15) : (wq > 0));
    const float* xh0 = x + (size_t)(b * C + g * 64 + hci) * (H * W) + gw;

    // ---- hoisted gates: s2[b, o, w] (h-independent) ----
    const int o = g * 64 + wave * 16 + col;
    const float4 g2a = *(const float4*)(s2 + ((size_t)b * C + o) * W + wq * 32 + q * 4);
    const float4 g2b = *(const float4*)(s2 + ((size_t)b * C + o) * W + wq * 32 + q * 4 + 16);

    P_LOADX(a0, hv0, h0);
    P_WRITEX(a0, hv0, xsb[0]);
    P_LOADX(a1, hv1, h0 + 1);
    P_LOADX(a0, hv0, h0 + 2);
    __syncthreads();

#define A_STEP(hh, CUR, AW, HW, AL, HL)                                        \
    {                                                                          \
        const int h = h0 + (hh);                                               \
        f32x4 acc[2];                                                          \
        acc[0] = (f32x4){0.f, 0.f, 0.f, 0.f};                                  \
        acc[1] = (f32x4){0.f, 0.f, 0.f, 0.f};                                  \
        {                                                                      \
            const char* ab = xsb[CUR] + q * 16;                                \
            _Pragma("unroll") for (int wt = 0; wt < 2; ++wt)                   \
                _Pragma("unroll") for (int kk = 0; kk < 2; ++kk)               \
                    _Pragma("unroll") for (int tap = 0; tap < 3; ++tap) {      \
                        const bf16x8 xf = *(const bf16x8*)(                    \
                            ab + (size_t)(wt * 16 + col + tap) * 144 +         \
                            kk * 64);                                          \
                        acc[wt] = __builtin_amdgcn_mfma_f32_16x16x32_bf16(     \
                            xf, wfr[tap][kk], acc[wt], 0, 0, 0);               \
                    }                                                          \
        }                                                                      \
        const float4 g1a =                                                     \
            *(const float4*)(s1 + ((size_t)b * H + h) * W + wq * 32 + q * 4);  \
        const float4 g1b = *(const float4*)(s1 + ((size_t)b * H + h) * W +     \
                                            wq * 32 + q * 4 + 16);             \
        const float g3v = s3[((size_t)b * H + h) * C + o];                     \
        const float k   = 1.f / 3.f;                                           \
        float* ob = out + ((size_t)(b * C + o) * H + h) * W + wq * 32 + q * 4; \
        f32x4 o0, o1;                                                          \
        o0[0] = acc[0][0] * (g1a.x + g2a.x + g3v) * k;                         \
        o0[1] = acc[0][1] * (g1a.y + g2a.y + g3v) * k;                         \
        o0[2] = acc[0][2] * (g1a.z + g2a.z + g3v) * k;                         \
        o0[3] = acc[0][3] * (g1a.w + g2a.w + g3v) * k;                         \
        o1[0] = acc[1][0] * (g1b.x + g2b.x + g3v) * k;                         \
        o1[1] = acc[1][1] * (g1b.y + g2b.y + g3v) * k;                         \
        o1[2] = acc[1][2] * (g1b.z + g2b.z + g3v) * k;                         \
        o1[3] = acc[1][3] * (g1b.w + g2b.w + g3v) * k;                         \
        *(f32x4*)ob        = o0;                                               \
        *(f32x4*)(ob + 16) = o1;                                               \
        if ((hh) < 7) P_WRITEX(AW, HW, xsb[(CUR) ^ 1]);                        \
        if ((hh) < 5) P_LOADX(AL, HL, h0 + (hh) + 3);                          \
        __syncthreads();                                                       \
    }

    for (int hh = 0; hh < 8; hh += 2) {
        A_STEP(hh,     0, a1, hv1, a1, hv1);
        A_STEP(hh + 1, 1, a0, hv0, a0, hv0);
    }
#undef A_STEP
#undef P_LOADX
#undef P_WRITEX
}

// ---------------- combine: pool3 only (16-way) ----------------
__global__ __launch_bounds__(256) void combine(const unsigned* __restrict__ p3p,
                                               float* __restrict__ pool3) {
    const int n = blockIdx.x * 256 + threadIdx.x;   // over B*H*C
    const int b = n >> 12;
    const int o = n & 4095;
    float m = -INFINITY, s = 0.f;
#pragma unroll
    for (int wq = 0; wq < 16; ++wq) {
        const unsigned u = p3p[(size_t)(wq * B + b) * 4096 + o];
        m = fmaxf(m, bflo(u));
        s += bfhi(u);
    }
    pool3[((size_t)(b * 2 + 0) * H * C) + o] = m;
    pool3[((size_t)(b * 2 + 1) * H * C) + o] = s * (1.f / W);
}

// ---------------- gates: three 7x7 conv (2->1) + sigmoid in one kernel ------------
// s1 reads pool1p (2 packed partials), s2 reads pool2p (2 packed partials),
// s3 reads combined pool3 (f32, 2 planes).
__global__ __launch_bounds__(256) void gates(
    const unsigned* __restrict__ pool1p, const unsigned* __restrict__ pool2p,
    const float* __restrict__ pool3, const float* __restrict__ w1,
    const float* __restrict__ w2, const float* __restrict__ w3,
    float* __restrict__ s1, float* __restrict__ s2, float* __restrict__ s3) {
    const int bid = blockIdx.x;
    if (bid < 256) {
        // ---- s1: 2-way packed partials, P=H, Q=W, mean scale 1/C ----
        const int n  = bid * 256 + threadIdx.x;     // over B*H*W/4
        const int q0 = (n & 127) * 4;
        const int p  = (n >> 7) & 31;
        const int b  = n >> 12;
        float acc0 = 0.f, acc1 = 0.f, acc2 = 0.f, acc3 = 0.f;
#pragma unroll
        for (int i = 0; i < 7; ++i) {
            const int pp = p + i - 3;
            if (pp < 0 || pp >= H) continue;
            const unsigned* r0 = pool1p + ((size_t)b * H + pp) * W;
            const unsigned* r1 = r0 + 262144;
            float vm[10], vs[10];
#pragma unroll
            for (int j = 0; j < 10; ++j) {
                const int qq = q0 + j - 3;
                const unsigned u0 = (qq >= 0 && qq < W) ? r0[qq] : 0u;
                const unsigned u1 = (qq >= 0 && qq < W) ? r1[qq] : 0u;
                vm[j] = fmaxf(bflo(u0), bflo(u1));
                vs[j] = (bfhi(u0) + bfhi(u1)) * (1.f / C);
            }
            const float* wr0 = w1 + i * 7;
            const float* wr1 = w1 + 49 + i * 7;
#pragma unroll
            for (int j = 0; j < 7; ++j) {
                const float wv0 = wr0[j], wv1 = wr1[j];
                acc0 += vm[j]     * wv0 + vs[j]     * wv1;
                acc1 += vm[j + 1] * wv0 + vs[j + 1] * wv1;
                acc2 += vm[j + 2] * wv0 + vs[j + 2] * wv1;
                acc3 += vm[j + 3] * wv0 + vs[j + 3] * wv1;
            }
        }
        float4 ov;
        ov.x = 1.f / (1.f + expf(-acc0));
        ov.y = 1.f / (1.f + expf(-acc1));
        ov.z = 1.f / (1.f + expf(-acc2));
        ov.w = 1.f / (1.f + expf(-acc3));
        *(float4*)(s1 + (size_t)n * 4) = ov;
    } else if (bid < 1280) {
        // ---- s2: 2-way packed partials, P=C, Q=W, mean scale 1/H ----
        const int n  = (bid - 256) * 256 + threadIdx.x;   // over B*C*W/4
        const int q0 = (n & 127) * 4;
        const int p  = (n >> 7) & 127;
        const int b  = n >> 14;
        float acc0 = 0.f, acc1 = 0.f, acc2 = 0.f, acc3 = 0.f;
#pragma unroll
        for (int i = 0; i < 7; ++i) {
            const int pp = p + i - 3;
            if (pp < 0 || pp >= C) continue;
            const unsigned* r0 = pool2p + ((size_t)b * C + pp) * W;
            const unsigned* r1 = r0 + 1048576;
            float vm[10], vs[10];
#pragma unroll
            for (int j = 0; j < 10; ++j) {
                const int qq = q0 + j - 3;
                const unsigned u0 = (qq >= 0 && qq < W) ? r0[qq] : 0u;
                const unsigned u1 = (qq >= 0 && qq < W) ? r1[qq] : 0u;
                vm[j] = fmaxf(bflo(u0), bflo(u1));
                vs[j] = (bfhi(u0) + bfhi(u1)) * (1.f / H);
            }
            const float* wr0 = w2 + i * 7;
            const float* wr1 = w2 + 49 + i * 7;
#pragma unroll
            for (int j = 0; j < 7; ++j) {
                const float wv0 = wr0[j], wv1 = wr1[j];
                acc0 += vm[j]     * wv0 + vs[j]     * wv1;
                acc1 += vm[j + 1] * wv0 + vs[j + 1] * wv1;
                acc2 += vm[j + 2] * wv0 + vs[j + 2] * wv1;
                acc3 += vm[j + 3] * wv0 + vs[j + 3] * wv1;
            }
        }
        float4 ov;
        ov.x = 1.f / (1.f + expf(-acc0));
        ov.y = 1.f / (1.f + expf(-acc1));
        ov.z = 1.f / (1.f + expf(-acc2));
        ov.w = 1.f / (1.f + expf(-acc3));
        *(float4*)(s2 + (size_t)n * 4) = ov;
    } else {
        // ---- s3: combined pool3 (f32 2 planes), P=H, Q=C ----
        const int n  = (bid - 1280) * 256 + threadIdx.x;  // over B*H*C/4
        const int q0 = (n & 31) * 4;
        const int p  = (n >> 5) & 31;
        const int b  = n >> 10;
        float acc0 = 0.f, acc1 = 0.f, acc2 = 0.f, acc3 = 0.f;
#pragma unroll
        for (int c2 = 0; c2 < 2; ++c2) {
#pragma unroll
            for (int i = 0; i < 7; ++i) {
                const int pp = p + i - 3;
                if (pp < 0 || pp >= H) continue;
                const float* row = pool3 + ((size_t)(b * 2 + c2) * H + pp) * C;
                float win[10];
#pragma unroll
                for (int j = 0; j < 10; ++j) {
                    const int qq = q0 + j - 3;
                    win[j] = (qq >= 0 && qq < C) ? row[qq] : 0.f;
                }
                const float* wr = w3 + c2 * 49 + i * 7;
#pragma unroll
                for (int j = 0; j < 7; ++j) {
                    const float wv = wr[j];
                    acc0 += win[j]     * wv;
                    acc1 += win[j + 1] * wv;
                    acc2 += win[j + 2] * wv;
                    acc3 += win[j + 3] * wv;
                }
            }
        }
        float4 ov;
        ov.x = 1.f / (1.f + expf(-acc0));
        ov.y = 1.f / (1.f + expf(-acc1));
        ov.z = 1.f / (1.f + expf(-acc2));
        ov.w = 1.f / (1.f + expf(-acc3));
        *(float4*)(s3 + (size_t)n * 4) = ov;
    }
}

extern "C" void kernel_launch(void* const* d_in, const int* in_sizes, int n_in,
                              void* d_out, int out_size, void* d_ws, size_t ws_size,
                              hipStream_t stream) {
    const float* x  = (const float*)d_in[0];
    const float* wg = (const float*)d_in[1];
    const float* w1 = (const float*)d_in[2];
    const float* w2 = (const float*)d_in[3];
    const float* w3 = (const float*)d_in[4];
    float* out = (float*)d_out;
    float* ws  = (float*)d_ws;

    // Workspace (float-slot offsets), total 4,141,056 floats = 16.56 MB:
    //  [0,       524288): pool1p u32 [2][B][H][W]   (live until gates)
    //  [524288, 1572864): pool3p u32 [16][B][H][C]  -> s2 reuses after combine
    //  [1572864,3670016): pool2p u32 [2][B][C][W]   (live until gates)
    //  [3670016,3801088): pool3 f32 [B][2][H][C]
    //  [3813376,4075520): s1 f32 [B][H][W]
    //  [4075520,4141056): s3 f32 [B][H][C]
    unsigned* pool1p = (unsigned*)ws;
    unsigned* pool3p = (unsigned*)(ws + 524288);
    unsigned* pool2p = (unsigned*)(ws + 1572864);
    float* pool3 = ws + 3670016;
    float* s1 = ws + 3813376;
    float* s3 = ws + 4075520;
    float* s2 = ws + 524288;          // overlays dead pool3p after combine

    conv_pools<<<dim3(1024), 256, 0, stream>>>(x, wg, pool3p, pool1p, pool2p);
    combine<<<dim3(256), 256, 0, stream>>>(pool3p, pool3);
    gates<<<dim3(1344), 256, 0, stream>>>(pool1p, pool2p, pool3, w1, w2, w3, s1, s2, s3);
    conv_apply<<<dim3(2048), 256, 0, stream>>>(x, wg, s1, s2, s3, out);
}